// Round 1
// baseline (586.670 us; speedup 1.0000x reference)
//
#include <hip/hip_runtime.h>
#include <stdint.h>

#define B_ 2
#define S_ 2048
#define D_ 1024
#define H_ 16
#define HD_ 64
#define SCALE_ 0.125f

typedef __bf16 bf16_t;
typedef bf16_t bf16x8 __attribute__((ext_vector_type(8)));
typedef float f32x4 __attribute__((ext_vector_type(4)));
typedef unsigned short u16x8 __attribute__((ext_vector_type(8)));
typedef unsigned short u16x4 __attribute__((ext_vector_type(4)));

static __device__ __forceinline__ unsigned short f2b(float f) {
  union { float f; uint32_t u; } v; v.f = f;
  uint32_t u = v.u;
  uint32_t r = (u + 0x7fffu + ((u >> 16) & 1u)) >> 16;  // RNE
  return (unsigned short)r;
}

static __device__ __forceinline__ bf16x8 asb(u16x8 u) {
  return __builtin_bit_cast(bf16x8, u);
}

// ---------------- cast fp32 -> bf16 (vectorized) ----------------
__global__ void cast_kernel(const float* __restrict__ src,
                            unsigned short* __restrict__ dst, int n) {
  int i = (blockIdx.x * blockDim.x + threadIdx.x) * 4;
  if (i >= n) return;
  float4 f = *(const float4*)(src + i);
  u16x4 o;
  o[0] = f2b(f.x); o[1] = f2b(f.y); o[2] = f2b(f.z); o[3] = f2b(f.w);
  *(u16x4*)(dst + i) = o;
}

// ---------------- bf16 GEMM: C = A[M,K] @ W[N,K]^T + bias ----------------
// OUTMODE 0: write bf16 in head-split layout [B,H,S,HD]; z selects q/k/v set.
// OUTMODE 1: write fp32 row-major [M,N].
template<int OUTMODE>
__global__ __launch_bounds__(256)
void gemm_bt(const unsigned short* __restrict__ Ab,
             const unsigned short* __restrict__ Wb,
             const float* __restrict__ biasb,
             void* __restrict__ outv,
             int M, int N, int K) {
  const int z = blockIdx.z;
  const unsigned short* A = Ab + (size_t)z * M * K;
  const unsigned short* W = Wb + (size_t)z * N * K;
  const float* bias = biasb + (size_t)z * N;

  __shared__ __align__(16) unsigned short As[128 * 32];
  __shared__ __align__(16) unsigned short Bs[128 * 32];

  const int tid = threadIdx.x;
  const int lane = tid & 63;
  const int wave = tid >> 6;
  const int wm = wave >> 1, wn = wave & 1;
  const int row0 = blockIdx.x * 128;
  const int col0 = blockIdx.y * 128;

  const int srow = tid >> 2;        // 0..63
  const int scol = (tid & 3) * 8;   // 0,8,16,24
  const int lr = lane & 15;
  const int lk = (lane >> 4) * 8;

  f32x4 acc[4][4] = {};

  for (int k0 = 0; k0 < K; k0 += 32) {
    u16x8 a0 = *(const u16x8*)&A[(size_t)(row0 + srow) * K + k0 + scol];
    u16x8 a1 = *(const u16x8*)&A[(size_t)(row0 + srow + 64) * K + k0 + scol];
    u16x8 b0 = *(const u16x8*)&W[(size_t)(col0 + srow) * K + k0 + scol];
    u16x8 b1 = *(const u16x8*)&W[(size_t)(col0 + srow + 64) * K + k0 + scol];
    __syncthreads();   // prior iteration's LDS reads complete
    *(u16x8*)&As[srow * 32 + scol] = a0;
    *(u16x8*)&As[(srow + 64) * 32 + scol] = a1;
    *(u16x8*)&Bs[srow * 32 + scol] = b0;
    *(u16x8*)&Bs[(srow + 64) * 32 + scol] = b1;
    __syncthreads();

    bf16x8 af[4], bfr[4];
#pragma unroll
    for (int i = 0; i < 4; ++i)
      af[i] = asb(*(const u16x8*)&As[(wm * 64 + i * 16 + lr) * 32 + lk]);
#pragma unroll
    for (int j = 0; j < 4; ++j)
      bfr[j] = asb(*(const u16x8*)&Bs[(wn * 64 + j * 16 + lr) * 32 + lk]);
#pragma unroll
    for (int i = 0; i < 4; ++i)
#pragma unroll
      for (int j = 0; j < 4; ++j)
        acc[i][j] = __builtin_amdgcn_mfma_f32_16x16x32_bf16(af[i], bfr[j], acc[i][j], 0, 0, 0);
  }

  const int lg = lane >> 4;
#pragma unroll
  for (int i = 0; i < 4; ++i) {
#pragma unroll
    for (int j = 0; j < 4; ++j) {
#pragma unroll
      for (int r = 0; r < 4; ++r) {
        int row = row0 + wm * 64 + i * 16 + lg * 4 + r;
        int col = col0 + wn * 64 + j * 16 + lr;
        float v = acc[i][j][r] + bias[col];
        if (OUTMODE == 0) {
          unsigned short* O = (unsigned short*)outv + (size_t)z * M * N;
          int b = row >> 11, s = row & 2047;
          int h = col >> 6, hd = col & 63;
          O[(((size_t)b * H_ + h) * S_ + s) * HD_ + hd] = f2b(v);
        } else {
          float* O = (float*)outv;
          O[(size_t)row * N + col] = v;
        }
      }
    }
  }
}

// ---------------- attention pass 1: per-row max m and sumexp l ----------------
__global__ __launch_bounds__(256)
void attn_pass1(const unsigned short* __restrict__ q_bh,
                const unsigned short* __restrict__ k_bh,
                const int* __restrict__ mask,
                float2* __restrict__ ml) {
  const int bh = blockIdx.y;
  const int b = bh >> 4;   // H_=16
  const int q0 = blockIdx.x * 64;

  __shared__ __align__(16) unsigned short Qs[64 * 64];
  __shared__ __align__(16) unsigned short Ks[64 * 64];

  const int tid = threadIdx.x, lane = tid & 63, wave = tid >> 6;
  const int srow = tid >> 3, scol = (tid & 7) * 8;
  const int lr = lane & 15, lg = lane >> 4, lk = lg * 8;

  const unsigned short* qb = q_bh + ((size_t)bh * S_ + q0) * HD_;
  *(u16x8*)&Qs[srow * 64 + scol] = *(const u16x8*)&qb[srow * 64 + scol];
  *(u16x8*)&Qs[(srow + 32) * 64 + scol] = *(const u16x8*)&qb[(srow + 32) * 64 + scol];
  __syncthreads();
  bf16x8 qf0 = asb(*(const u16x8*)&Qs[(wave * 16 + lr) * 64 + lk]);
  bf16x8 qf1 = asb(*(const u16x8*)&Qs[(wave * 16 + lr) * 64 + 32 + lk]);

  float m_r[4] = {-__builtin_inff(), -__builtin_inff(), -__builtin_inff(), -__builtin_inff()};
  float l_r[4] = {0.f, 0.f, 0.f, 0.f};

  const int* mrow = mask + (size_t)b * S_ * S_;
  const int si0 = q0 + wave * 16 + lg * 4;

  for (int kt = 0; kt < S_ / 64; ++kt) {
    const int k0 = kt * 64;
    const unsigned short* kb = k_bh + ((size_t)bh * S_ + k0) * HD_;
    u16x8 t0 = *(const u16x8*)&kb[srow * 64 + scol];
    u16x8 t1 = *(const u16x8*)&kb[(srow + 32) * 64 + scol];
    __syncthreads();
    *(u16x8*)&Ks[srow * 64 + scol] = t0;
    *(u16x8*)&Ks[(srow + 32) * 64 + scol] = t1;
    __syncthreads();

    f32x4 sa[4] = {};
#pragma unroll
    for (int j = 0; j < 4; ++j) {
      bf16x8 kf0 = asb(*(const u16x8*)&Ks[(j * 16 + lr) * 64 + lk]);
      bf16x8 kf1 = asb(*(const u16x8*)&Ks[(j * 16 + lr) * 64 + 32 + lk]);
      sa[j] = __builtin_amdgcn_mfma_f32_16x16x32_bf16(qf0, kf0, sa[j], 0, 0, 0);
      sa[j] = __builtin_amdgcn_mfma_f32_16x16x32_bf16(qf1, kf1, sa[j], 0, 0, 0);
    }

    float sv[4][4];
#pragma unroll
    for (int j = 0; j < 4; ++j) {
      int sj = k0 + j * 16 + lr;
#pragma unroll
      for (int r = 0; r < 4; ++r) {
        float v = sa[j][r] * SCALE_;
        int mk = mrow[(size_t)(si0 + r) * S_ + sj];
        sv[j][r] = mk ? v : -1e9f;
      }
    }
#pragma unroll
    for (int r = 0; r < 4; ++r) {
      float mx = fmaxf(fmaxf(sv[0][r], sv[1][r]), fmaxf(sv[2][r], sv[3][r]));
#pragma unroll
      for (int o = 1; o < 16; o <<= 1) mx = fmaxf(mx, __shfl_xor(mx, o));
      float mnew = fmaxf(m_r[r], mx);
      float ssum = __expf(sv[0][r] - mnew) + __expf(sv[1][r] - mnew) +
                   __expf(sv[2][r] - mnew) + __expf(sv[3][r] - mnew);
#pragma unroll
      for (int o = 1; o < 16; o <<= 1) ssum += __shfl_xor(ssum, o);
      l_r[r] = l_r[r] * __expf(m_r[r] - mnew) + ssum;
      m_r[r] = mnew;
    }
  }
  if (lr == 0) {
#pragma unroll
    for (int r = 0; r < 4; ++r)
      ml[(size_t)bh * S_ + si0 + r] = make_float2(m_r[r], l_r[r]);
  }
}

// ---------------- attention pass 2: weights write + PV ----------------
__global__ __launch_bounds__(256)
void attn_pass2(const unsigned short* __restrict__ q_bh,
                const unsigned short* __restrict__ k_bh,
                const unsigned short* __restrict__ v_bh,
                const int* __restrict__ mask,
                const float2* __restrict__ ml,
                float* __restrict__ w_out,
                unsigned short* __restrict__ attn_out) {
  const int bh = blockIdx.y;
  const int b = bh >> 4;
  const int h = bh & (H_ - 1);
  const int q0 = blockIdx.x * 64;

  __shared__ __align__(16) unsigned short Qs[64 * 64];
  __shared__ __align__(16) unsigned short Ks[64 * 64];
  __shared__ __align__(16) unsigned short Vt[64 * 64];
  __shared__ __align__(16) unsigned short Ps[4][16 * 64];

  const int tid = threadIdx.x, lane = tid & 63, wave = tid >> 6;
  const int srow = tid >> 3, scol = (tid & 7) * 8;
  const int lr = lane & 15, lg = lane >> 4, lk = lg * 8;

  const unsigned short* qb = q_bh + ((size_t)bh * S_ + q0) * HD_;
  *(u16x8*)&Qs[srow * 64 + scol] = *(const u16x8*)&qb[srow * 64 + scol];
  *(u16x8*)&Qs[(srow + 32) * 64 + scol] = *(const u16x8*)&qb[(srow + 32) * 64 + scol];
  __syncthreads();
  bf16x8 qf0 = asb(*(const u16x8*)&Qs[(wave * 16 + lr) * 64 + lk]);
  bf16x8 qf1 = asb(*(const u16x8*)&Qs[(wave * 16 + lr) * 64 + 32 + lk]);

  const int si0 = q0 + wave * 16 + lg * 4;
  float m_r[4], il_r[4];
#pragma unroll
  for (int r = 0; r < 4; ++r) {
    float2 t = ml[(size_t)bh * S_ + si0 + r];
    m_r[r] = t.x;
    il_r[r] = 1.0f / t.y;
  }

  const int* mrow = mask + (size_t)b * S_ * S_;
  f32x4 oacc[4] = {};

  for (int kt = 0; kt < S_ / 64; ++kt) {
    const int k0 = kt * 64;
    const unsigned short* kb = k_bh + ((size_t)bh * S_ + k0) * HD_;
    const unsigned short* vb = v_bh + ((size_t)bh * S_ + k0) * HD_;
    u16x8 t0 = *(const u16x8*)&kb[srow * 64 + scol];
    u16x8 t1 = *(const u16x8*)&kb[(srow + 32) * 64 + scol];
    u16x8 v0 = *(const u16x8*)&vb[srow * 64 + scol];
    u16x8 v1 = *(const u16x8*)&vb[(srow + 32) * 64 + scol];
    __syncthreads();   // previous iteration PV reads complete
    *(u16x8*)&Ks[srow * 64 + scol] = t0;
    *(u16x8*)&Ks[(srow + 32) * 64 + scol] = t1;
#pragma unroll
    for (int e = 0; e < 8; ++e) {
      Vt[(scol + e) * 64 + srow] = v0[e];
      Vt[(scol + e) * 64 + srow + 32] = v1[e];
    }
    __syncthreads();

    f32x4 sa[4] = {};
#pragma unroll
    for (int j = 0; j < 4; ++j) {
      bf16x8 kf0 = asb(*(const u16x8*)&Ks[(j * 16 + lr) * 64 + lk]);
      bf16x8 kf1 = asb(*(const u16x8*)&Ks[(j * 16 + lr) * 64 + 32 + lk]);
      sa[j] = __builtin_amdgcn_mfma_f32_16x16x32_bf16(qf0, kf0, sa[j], 0, 0, 0);
      sa[j] = __builtin_amdgcn_mfma_f32_16x16x32_bf16(qf1, kf1, sa[j], 0, 0, 0);
    }

#pragma unroll
    for (int j = 0; j < 4; ++j) {
      int sj = k0 + j * 16 + lr;
#pragma unroll
      for (int r = 0; r < 4; ++r) {
        float v = sa[j][r] * SCALE_;
        int mk = mrow[(size_t)(si0 + r) * S_ + sj];
        v = mk ? v : -1e9f;
        float p = __expf(v - m_r[r]) * il_r[r];
        w_out[((size_t)bh * S_ + (si0 + r)) * S_ + sj] = p;
        Ps[wave][(lg * 4 + r) * 64 + j * 16 + lr] = f2b(p);
      }
    }
    __syncthreads();   // Ps + Vt visible for PV

#pragma unroll
    for (int ks = 0; ks < 2; ++ks) {
      bf16x8 pa = asb(*(const u16x8*)&Ps[wave][lr * 64 + ks * 32 + lk]);
#pragma unroll
      for (int j2 = 0; j2 < 4; ++j2) {
        bf16x8 vbf = asb(*(const u16x8*)&Vt[(j2 * 16 + lr) * 64 + ks * 32 + lk]);
        oacc[j2] = __builtin_amdgcn_mfma_f32_16x16x32_bf16(pa, vbf, oacc[j2], 0, 0, 0);
      }
    }
  }

#pragma unroll
  for (int j2 = 0; j2 < 4; ++j2) {
#pragma unroll
    for (int r = 0; r < 4; ++r) {
      int s = si0 + r;
      int hd = j2 * 16 + lr;
      attn_out[((size_t)b * S_ + s) * D_ + h * HD_ + hd] = f2b(oacc[j2][r]);
    }
  }
}

// ---------------- launch ----------------
extern "C" void kernel_launch(void* const* d_in, const int* in_sizes, int n_in,
                              void* d_out, int out_size, void* d_ws, size_t ws_size,
                              hipStream_t stream) {
  const float* query = (const float*)d_in[0];
  const float* key   = (const float*)d_in[1];
  const float* value = (const float*)d_in[2];
  const int*   mask  = (const int*)d_in[3];
  const float* Wq = (const float*)d_in[4];
  const float* bq = (const float*)d_in[5];
  const float* Wk = (const float*)d_in[6];
  const float* bk = (const float*)d_in[7];
  const float* Wv = (const float*)d_in[8];
  const float* bv = (const float*)d_in[9];
  const float* Wo = (const float*)d_in[10];
  const float* bo = (const float*)d_in[11];

  const int NE = B_ * S_ * D_;   // 4194304
  const int NW = D_ * D_;        // 1048576

  char* ws = (char*)d_ws;
  unsigned short* xin  = (unsigned short*)(ws);                       // 3*NE bf16
  unsigned short* wbuf = (unsigned short*)(ws + 25165824);            // 4*NW bf16
  float* biasws        = (float*)(ws + 25165824 + 8388608);           // 4*1024 f32
  unsigned short* qkv  = (unsigned short*)(ws + 33570816);            // 3*NE bf16
  float2* mlbuf        = (float2*)(ws + 58736640);                    // 65536 float2
  unsigned short* aout = (unsigned short*)(ws + 59260928);            // NE bf16

  cast_kernel<<<dim3(NE / 1024), dim3(256), 0, stream>>>(query, xin, NE);
  cast_kernel<<<dim3(NE / 1024), dim3(256), 0, stream>>>(key,   xin + NE, NE);
  cast_kernel<<<dim3(NE / 1024), dim3(256), 0, stream>>>(value, xin + 2 * NE, NE);
  cast_kernel<<<dim3(NW / 1024), dim3(256), 0, stream>>>(Wq, wbuf, NW);
  cast_kernel<<<dim3(NW / 1024), dim3(256), 0, stream>>>(Wk, wbuf + NW, NW);
  cast_kernel<<<dim3(NW / 1024), dim3(256), 0, stream>>>(Wv, wbuf + 2 * NW, NW);
  cast_kernel<<<dim3(NW / 1024), dim3(256), 0, stream>>>(Wo, wbuf + 3 * NW, NW);
  hipMemcpyAsync(biasws,        bq, 4096, hipMemcpyDeviceToDevice, stream);
  hipMemcpyAsync(biasws + 1024, bk, 4096, hipMemcpyDeviceToDevice, stream);
  hipMemcpyAsync(biasws + 2048, bv, 4096, hipMemcpyDeviceToDevice, stream);
  hipMemcpyAsync(biasws + 3072, bo, 4096, hipMemcpyDeviceToDevice, stream);

  // q,k,v projections (z = 0,1,2)
  gemm_bt<0><<<dim3(32, 8, 3), dim3(256), 0, stream>>>(
      xin, wbuf, biasws, qkv, 4096, 1024, 1024);

  float* w_out = (float*)d_out + NE;   // attn_weights region
  attn_pass1<<<dim3(32, 32), dim3(256), 0, stream>>>(qkv, qkv + NE, mask, mlbuf);
  attn_pass2<<<dim3(32, 32), dim3(256), 0, stream>>>(
      qkv, qkv + NE, qkv + 2 * NE, mask, mlbuf, w_out, aout);

  // output projection -> fp32 d_out
  gemm_bt<1><<<dim3(32, 8, 1), dim3(256), 0, stream>>>(
      aout, wbuf + 3 * NW, bo, d_out, 4096, 1024, 1024);
}

// Round 2
// 360.745 us; speedup vs baseline: 1.6263x; 1.6263x over previous
//
#include <hip/hip_runtime.h>
#include <stdint.h>

#define B_ 2
#define S_ 2048
#define D_ 1024
#define H_ 16
#define HD_ 64
#define SCALE_ 0.125f
#define NT_ (S_ / 64)

typedef __bf16 bf16_t;
typedef bf16_t bf16x8 __attribute__((ext_vector_type(8)));
typedef float f32x4 __attribute__((ext_vector_type(4)));
typedef unsigned short u16x8 __attribute__((ext_vector_type(8)));
typedef unsigned short u16x4 __attribute__((ext_vector_type(4)));

static __device__ __forceinline__ unsigned short f2b(float f) {
  union { float f; uint32_t u; } v; v.f = f;
  uint32_t u = v.u;
  uint32_t r = (u + 0x7fffu + ((u >> 16) & 1u)) >> 16;  // RNE
  return (unsigned short)r;
}

static __device__ __forceinline__ bf16x8 asb(u16x8 u) {
  return __builtin_bit_cast(bf16x8, u);
}

// ---------------- cast fp32 -> bf16 (8 elems/thread) ----------------
__global__ void cast_kernel(const float* __restrict__ src,
                            unsigned short* __restrict__ dst, int n) {
  int i = (blockIdx.x * blockDim.x + threadIdx.x) * 8;
  if (i >= n) return;
  float4 f0 = *(const float4*)(src + i);
  float4 f1 = *(const float4*)(src + i + 4);
  u16x8 o;
  o[0] = f2b(f0.x); o[1] = f2b(f0.y); o[2] = f2b(f0.z); o[3] = f2b(f0.w);
  o[4] = f2b(f1.x); o[5] = f2b(f1.y); o[6] = f2b(f1.z); o[7] = f2b(f1.w);
  *(u16x8*)(dst + i) = o;
}

// ---------------- pack mask to bits via ballot ----------------
__global__ void pack_mask(const int* __restrict__ mask,
                          uint32_t* __restrict__ mbits) {
  int i = blockIdx.x * blockDim.x + threadIdx.x;   // one int per lane
  unsigned long long bits = __ballot(mask[i] != 0);
  if ((threadIdx.x & 63) == 0)
    *(unsigned long long*)&mbits[i >> 5] = bits;
}

// ---------------- transpose V per head: [bh][s][64] -> [bh][64][s] ----------------
__global__ __launch_bounds__(256)
void transpose_v(const unsigned short* __restrict__ v_bh,
                 unsigned short* __restrict__ vt) {
  const int bh = blockIdx.y;
  const int s0 = blockIdx.x * 64;
  __shared__ __align__(16) unsigned short T[64 * 72];
  const int tid = threadIdx.x;
  const int r = tid >> 3, c = (tid & 7) * 8;
  const unsigned short* src = v_bh + ((size_t)bh * S_ + s0) * HD_;
  *(u16x8*)&T[r * 72 + c] = *(const u16x8*)&src[r * 64 + c];
  *(u16x8*)&T[(r + 32) * 72 + c] = *(const u16x8*)&src[(r + 32) * 64 + c];
  __syncthreads();
  const int hd = tid & 63;
  const int sc = (tid >> 6) * 16;
  u16x8 o0, o1;
#pragma unroll
  for (int i = 0; i < 8; ++i) o0[i] = T[(sc + i) * 72 + hd];
#pragma unroll
  for (int i = 0; i < 8; ++i) o1[i] = T[(sc + 8 + i) * 72 + hd];
  unsigned short* drow = vt + ((size_t)bh * HD_ + hd) * S_ + s0 + sc;
  *(u16x8*)&drow[0] = o0;
  *(u16x8*)&drow[8] = o1;
}

// ---------------- bf16 GEMM: C = A[M,K] @ W[N,K]^T + bias ----------------
// OUTMODE 0: write bf16 head-split [B,H,S,HD]; z selects q/k/v.
// OUTMODE 1: write fp32 row-major [M,N].
template<int OUTMODE>
__global__ __launch_bounds__(256)
void gemm_bt(const unsigned short* __restrict__ Ab,
             const unsigned short* __restrict__ Wb,
             const float* __restrict__ biasb,
             void* __restrict__ outv,
             int M, int N, int K) {
  const int z = blockIdx.z;
  const unsigned short* A = Ab + (size_t)z * M * K;
  const unsigned short* W = Wb + (size_t)z * N * K;
  const float* bias = biasb + (size_t)z * N;

  // padded stride 40 u16 = 80B (5 mod 8 -> 2-way bank spread on b128 reads)
  __shared__ __align__(16) unsigned short As[128 * 40];
  __shared__ __align__(16) unsigned short Bs[128 * 40];

  const int tid = threadIdx.x;
  const int lane = tid & 63;
  const int wave = tid >> 6;
  const int wm = wave >> 1, wn = wave & 1;
  const int row0 = blockIdx.x * 128;
  const int col0 = blockIdx.y * 128;

  const int srow = tid >> 2;        // 0..63
  const int scol = (tid & 3) * 8;   // 0,8,16,24
  const int lr = lane & 15;
  const int lg = lane >> 4;
  const int lk = lg * 8;

  f32x4 acc[4][4] = {};

  u16x8 a0 = *(const u16x8*)&A[(size_t)(row0 + srow) * K + scol];
  u16x8 a1 = *(const u16x8*)&A[(size_t)(row0 + srow + 64) * K + scol];
  u16x8 b0 = *(const u16x8*)&W[(size_t)(col0 + srow) * K + scol];
  u16x8 b1 = *(const u16x8*)&W[(size_t)(col0 + srow + 64) * K + scol];

  for (int k0 = 0; k0 < K; k0 += 32) {
    __syncthreads();   // prior iteration's LDS reads complete
    *(u16x8*)&As[srow * 40 + scol] = a0;
    *(u16x8*)&As[(srow + 64) * 40 + scol] = a1;
    *(u16x8*)&Bs[srow * 40 + scol] = b0;
    *(u16x8*)&Bs[(srow + 64) * 40 + scol] = b1;
    if (k0 + 32 < K) {
      a0 = *(const u16x8*)&A[(size_t)(row0 + srow) * K + k0 + 32 + scol];
      a1 = *(const u16x8*)&A[(size_t)(row0 + srow + 64) * K + k0 + 32 + scol];
      b0 = *(const u16x8*)&W[(size_t)(col0 + srow) * K + k0 + 32 + scol];
      b1 = *(const u16x8*)&W[(size_t)(col0 + srow + 64) * K + k0 + 32 + scol];
    }
    __syncthreads();

    bf16x8 af[4], bfr[4];
#pragma unroll
    for (int i = 0; i < 4; ++i)
      af[i] = asb(*(const u16x8*)&As[(wm * 64 + i * 16 + lr) * 40 + lk]);
#pragma unroll
    for (int j = 0; j < 4; ++j)
      bfr[j] = asb(*(const u16x8*)&Bs[(wn * 64 + j * 16 + lr) * 40 + lk]);
#pragma unroll
    for (int i = 0; i < 4; ++i)
#pragma unroll
      for (int j = 0; j < 4; ++j)
        acc[i][j] = __builtin_amdgcn_mfma_f32_16x16x32_bf16(af[i], bfr[j], acc[i][j], 0, 0, 0);
  }

#pragma unroll
  for (int i = 0; i < 4; ++i) {
#pragma unroll
    for (int j = 0; j < 4; ++j) {
#pragma unroll
      for (int r = 0; r < 4; ++r) {
        int row = row0 + wm * 64 + i * 16 + lg * 4 + r;
        int col = col0 + wn * 64 + j * 16 + lr;
        float v = acc[i][j][r] + bias[col];
        if (OUTMODE == 0) {
          unsigned short* O = (unsigned short*)outv + (size_t)z * M * N;
          int b = row >> 11, s = row & 2047;
          int h = col >> 6, hd = col & 63;
          O[(((size_t)b * H_ + h) * S_ + s) * HD_ + hd] = f2b(v);
        } else {
          float* O = (float*)outv;
          O[(size_t)row * N + col] = v;
        }
      }
    }
  }
}

// ---------------- attention pass 1: per-row (m, l) ----------------
// Swapped QK^T: sa = mfma(K, Q) -> D col = sq, row = sk. Lane owns ONE sq row.
__global__ __launch_bounds__(256)
void attn_pass1(const unsigned short* __restrict__ q_bh,
                const unsigned short* __restrict__ k_bh,
                const uint32_t* __restrict__ mbits,
                float2* __restrict__ ml) {
  const int bh = blockIdx.y;
  const int b = bh >> 4;
  const int q0 = blockIdx.x * 64;

  __shared__ __align__(16) unsigned short Ks[64 * 72];

  const int tid = threadIdx.x, lane = tid & 63, wave = tid >> 6;
  const int srow = tid >> 3, scol = (tid & 7) * 8;   // srow 0..31
  const int lr = lane & 15, lg = lane >> 4, lk = lg * 8;
  const int sq = q0 + wave * 16 + lr;

  // Q direct from global (coalesced 16B/lane)
  const unsigned short* qb = q_bh + ((size_t)bh * S_ + sq) * HD_;
  bf16x8 qf0 = asb(*(const u16x8*)&qb[lk]);
  bf16x8 qf1 = asb(*(const u16x8*)&qb[32 + lk]);

  const uint32_t* mrow = mbits + ((size_t)b * S_ + sq) * (S_ / 32);
  const unsigned short* kb = k_bh + (size_t)bh * S_ * HD_;

  float m = -__builtin_inff(), l = 0.f;

  u16x8 t0 = *(const u16x8*)&kb[srow * 64 + scol];
  u16x8 t1 = *(const u16x8*)&kb[(srow + 32) * 64 + scol];

  for (int kt = 0; kt < NT_; ++kt) {
    __syncthreads();
    *(u16x8*)&Ks[srow * 72 + scol] = t0;
    *(u16x8*)&Ks[(srow + 32) * 72 + scol] = t1;
    if (kt + 1 < NT_) {
      const unsigned short* kn = kb + (kt + 1) * 64 * 64;
      t0 = *(const u16x8*)&kn[srow * 64 + scol];
      t1 = *(const u16x8*)&kn[(srow + 32) * 64 + scol];
    }
    __syncthreads();

    uint2 mw = *(const uint2*)&mrow[kt * 2];
    f32x4 sa[4] = {};
#pragma unroll
    for (int j = 0; j < 4; ++j) {
      bf16x8 kf0 = asb(*(const u16x8*)&Ks[(j * 16 + lr) * 72 + lk]);
      bf16x8 kf1 = asb(*(const u16x8*)&Ks[(j * 16 + lr) * 72 + 32 + lk]);
      sa[j] = __builtin_amdgcn_mfma_f32_16x16x32_bf16(kf0, qf0, sa[j], 0, 0, 0);
      sa[j] = __builtin_amdgcn_mfma_f32_16x16x32_bf16(kf1, qf1, sa[j], 0, 0, 0);
    }

    float sv[4][4];
#pragma unroll
    for (int j = 0; j < 4; ++j) {
      uint32_t mwj = (j < 2) ? mw.x : mw.y;
#pragma unroll
      for (int r = 0; r < 4; ++r) {
        int bit = (j & 1) * 16 + lg * 4 + r;
        sv[j][r] = ((mwj >> bit) & 1) ? sa[j][r] * SCALE_ : -1e9f;
      }
    }
    float tm = sv[0][0];
#pragma unroll
    for (int j = 0; j < 4; ++j)
#pragma unroll
      for (int r = 0; r < 4; ++r) tm = fmaxf(tm, sv[j][r]);
    tm = fmaxf(tm, __shfl_xor(tm, 16));
    tm = fmaxf(tm, __shfl_xor(tm, 32));
    float mnew = fmaxf(m, tm);
    float ss = 0.f;
#pragma unroll
    for (int j = 0; j < 4; ++j)
#pragma unroll
      for (int r = 0; r < 4; ++r) ss += __expf(sv[j][r] - mnew);
    ss += __shfl_xor(ss, 16);
    ss += __shfl_xor(ss, 32);
    l = l * __expf(m - mnew) + ss;
    m = mnew;
  }
  if (lg == 0) ml[(size_t)bh * S_ + sq] = make_float2(m, l);
}

// ---------------- attention pass 2: normalized weights + PV ----------------
__global__ __launch_bounds__(256)
void attn_pass2(const unsigned short* __restrict__ q_bh,
                const unsigned short* __restrict__ k_bh,
                const unsigned short* __restrict__ vt_g,
                const uint32_t* __restrict__ mbits,
                const float2* __restrict__ ml,
                float* __restrict__ w_out,
                unsigned short* __restrict__ attn_out) {
  const int bh = blockIdx.y;
  const int b = bh >> 4, h = bh & (H_ - 1);
  const int q0 = blockIdx.x * 64;

  __shared__ __align__(16) unsigned short Ks[64 * 72];
  __shared__ __align__(16) unsigned short Vs[64 * 72];   // V^T tile: [hd][sk]
  __shared__ __align__(16) unsigned short Ps[4][16 * 72];

  const int tid = threadIdx.x, lane = tid & 63, wave = tid >> 6;
  const int srow = tid >> 3, scol = (tid & 7) * 8;
  const int lr = lane & 15, lg = lane >> 4, lk = lg * 8;
  const int sq = q0 + wave * 16 + lr;

  const unsigned short* qb = q_bh + ((size_t)bh * S_ + sq) * HD_;
  bf16x8 qf0 = asb(*(const u16x8*)&qb[lk]);
  bf16x8 qf1 = asb(*(const u16x8*)&qb[32 + lk]);

  float2 t = ml[(size_t)bh * S_ + sq];
  const float m = t.x;
  const float il = 1.0f / t.y;
  const uint32_t* mrow = mbits + ((size_t)b * S_ + sq) * (S_ / 32);
  float* wrow = w_out + ((size_t)bh * S_ + sq) * S_;

  const unsigned short* kb = k_bh + (size_t)bh * S_ * HD_;
  const unsigned short* vb = vt_g + (size_t)bh * HD_ * S_;

  u16x8 t0 = *(const u16x8*)&kb[srow * 64 + scol];
  u16x8 t1 = *(const u16x8*)&kb[(srow + 32) * 64 + scol];
  u16x8 v0 = *(const u16x8*)&vb[(size_t)srow * S_ + scol];
  u16x8 v1 = *(const u16x8*)&vb[(size_t)(srow + 32) * S_ + scol];

  f32x4 oacc[4] = {};

  for (int kt = 0; kt < NT_; ++kt) {
    const int k0 = kt * 64;
    __syncthreads();   // prior iteration's QK/PV LDS reads complete
    *(u16x8*)&Ks[srow * 72 + scol] = t0;
    *(u16x8*)&Ks[(srow + 32) * 72 + scol] = t1;
    *(u16x8*)&Vs[srow * 72 + scol] = v0;
    *(u16x8*)&Vs[(srow + 32) * 72 + scol] = v1;
    if (kt + 1 < NT_) {
      t0 = *(const u16x8*)&kb[(k0 + 64 + srow) * 64 + scol];
      t1 = *(const u16x8*)&kb[(k0 + 64 + srow + 32) * 64 + scol];
      v0 = *(const u16x8*)&vb[(size_t)srow * S_ + k0 + 64 + scol];
      v1 = *(const u16x8*)&vb[(size_t)(srow + 32) * S_ + k0 + 64 + scol];
    }
    __syncthreads();

    uint2 mw = *(const uint2*)&mrow[kt * 2];
    f32x4 sa[4] = {};
#pragma unroll
    for (int j = 0; j < 4; ++j) {
      bf16x8 kf0 = asb(*(const u16x8*)&Ks[(j * 16 + lr) * 72 + lk]);
      bf16x8 kf1 = asb(*(const u16x8*)&Ks[(j * 16 + lr) * 72 + 32 + lk]);
      sa[j] = __builtin_amdgcn_mfma_f32_16x16x32_bf16(kf0, qf0, sa[j], 0, 0, 0);
      sa[j] = __builtin_amdgcn_mfma_f32_16x16x32_bf16(kf1, qf1, sa[j], 0, 0, 0);
    }

    // softmax weights: lane owns row sq, sks = k0 + j*16 + lg*4 + r
#pragma unroll
    for (int j = 0; j < 4; ++j) {
      uint32_t mwj = (j < 2) ? mw.x : mw.y;
      f32x4 pv;
      u16x4 pb;
#pragma unroll
      for (int r = 0; r < 4; ++r) {
        int bit = (j & 1) * 16 + lg * 4 + r;
        float v = ((mwj >> bit) & 1) ? sa[j][r] * SCALE_ : -1e9f;
        float p = __expf(v - m) * il;
        pv[r] = p;
        pb[r] = f2b(p);
      }
      *(f32x4*)&wrow[k0 + j * 16 + lg * 4] = pv;                       // 16B store
      *(u16x4*)&Ps[wave][lr * 72 + j * 16 + lg * 4] = pb;              // 8B LDS write
    }

    // PV: A = P (row=sq), B = V^T tile (col=hd). Wave-private Ps, no barrier.
#pragma unroll
    for (int ks = 0; ks < 2; ++ks) {
      bf16x8 pa = asb(*(const u16x8*)&Ps[wave][lr * 72 + ks * 32 + lk]);
#pragma unroll
      for (int j2 = 0; j2 < 4; ++j2) {
        bf16x8 vf = asb(*(const u16x8*)&Vs[(j2 * 16 + lr) * 72 + ks * 32 + lk]);
        oacc[j2] = __builtin_amdgcn_mfma_f32_16x16x32_bf16(pa, vf, oacc[j2], 0, 0, 0);
      }
    }
  }

  // D: col = hd = j2*16+lr, row = sq-local = lg*4+r
#pragma unroll
  for (int j2 = 0; j2 < 4; ++j2)
#pragma unroll
    for (int r = 0; r < 4; ++r)
      attn_out[((size_t)b * S_ + q0 + wave * 16 + lg * 4 + r) * D_ + h * HD_ + j2 * 16 + lr] =
          f2b(oacc[j2][r]);
}

// ---------------- launch ----------------
extern "C" void kernel_launch(void* const* d_in, const int* in_sizes, int n_in,
                              void* d_out, int out_size, void* d_ws, size_t ws_size,
                              hipStream_t stream) {
  const float* query = (const float*)d_in[0];
  const float* key   = (const float*)d_in[1];
  const float* value = (const float*)d_in[2];
  const int*   mask  = (const int*)d_in[3];
  const float* Wq = (const float*)d_in[4];
  const float* bq = (const float*)d_in[5];
  const float* Wk = (const float*)d_in[6];
  const float* bk = (const float*)d_in[7];
  const float* Wv = (const float*)d_in[8];
  const float* bv = (const float*)d_in[9];
  const float* Wo = (const float*)d_in[10];
  const float* bo = (const float*)d_in[11];

  const int NE = B_ * S_ * D_;   // 4194304
  const int NW = D_ * D_;        // 1048576

  char* ws = (char*)d_ws;
  unsigned short* xin  = (unsigned short*)(ws);                 // [0, 25165824) - dead after proj gemm
  unsigned short* vt   = (unsigned short*)(ws);                 // reuses xin[0, 8388608)
  uint32_t*       mbits = (uint32_t*)(ws + 8388608);            // reuses xin[8388608, 9437184)
  unsigned short* wbuf = (unsigned short*)(ws + 25165824);      // 8388608
  float* biasws        = (float*)(ws + 33554432);               // 16384
  unsigned short* qkv  = (unsigned short*)(ws + 33570816);      // 25165824
  float2* mlbuf        = (float2*)(ws + 58736640);              // 524288
  unsigned short* aout = (unsigned short*)(ws + 59260928);      // 8388608

  cast_kernel<<<dim3(NE / 2048), dim3(256), 0, stream>>>(query, xin, NE);
  cast_kernel<<<dim3(NE / 2048), dim3(256), 0, stream>>>(key,   xin + NE, NE);
  cast_kernel<<<dim3(NE / 2048), dim3(256), 0, stream>>>(value, xin + 2 * NE, NE);
  cast_kernel<<<dim3(NW / 2048), dim3(256), 0, stream>>>(Wq, wbuf, NW);
  cast_kernel<<<dim3(NW / 2048), dim3(256), 0, stream>>>(Wk, wbuf + NW, NW);
  cast_kernel<<<dim3(NW / 2048), dim3(256), 0, stream>>>(Wv, wbuf + 2 * NW, NW);
  cast_kernel<<<dim3(NW / 2048), dim3(256), 0, stream>>>(Wo, wbuf + 3 * NW, NW);
  hipMemcpyAsync(biasws,        bq, 4096, hipMemcpyDeviceToDevice, stream);
  hipMemcpyAsync(biasws + 1024, bk, 4096, hipMemcpyDeviceToDevice, stream);
  hipMemcpyAsync(biasws + 2048, bv, 4096, hipMemcpyDeviceToDevice, stream);
  hipMemcpyAsync(biasws + 3072, bo, 4096, hipMemcpyDeviceToDevice, stream);

  // q,k,v projections (z = 0,1,2) -> head-split bf16
  gemm_bt<0><<<dim3(32, 8, 3), dim3(256), 0, stream>>>(
      xin, wbuf, biasws, qkv, 4096, 1024, 1024);

  // after proj gemm, xin region is dead: build mbits + vt there
  pack_mask<<<dim3(B_ * S_ * S_ / 256), dim3(256), 0, stream>>>(mask, mbits);
  transpose_v<<<dim3(32, 32), dim3(256), 0, stream>>>(qkv + 2 * NE, vt);

  float* w_out = (float*)d_out + NE;   // attn_weights region
  attn_pass1<<<dim3(32, 32), dim3(256), 0, stream>>>(qkv, qkv + NE, mbits, mlbuf);
  attn_pass2<<<dim3(32, 32), dim3(256), 0, stream>>>(
      qkv, qkv + NE, vt, mbits, mlbuf, w_out, aout);

  // output projection -> fp32 d_out
  gemm_bt<1><<<dim3(32, 8, 1), dim3(256), 0, stream>>>(
      aout, wbuf + 3 * NW, bo, d_out, 4096, 1024, 1024);
}